// Round 8
// baseline (217.489 us; speedup 1.0000x reference)
//
#include <hip/hip_runtime.h>
#include <math.h>

#define EMB 256

typedef _Float16 half8 __attribute__((ext_vector_type(8)));
typedef float f32x4 __attribute__((ext_vector_type(4)));

// ---------- async global->LDS, 16B per lane ----------
__device__ __forceinline__ void gload_lds16(const void* gsrc, void* lds) {
    __builtin_amdgcn_global_load_lds(
        (const __attribute__((address_space(1))) void*)gsrc,
        (__attribute__((address_space(3))) void*)lds,
        16, 0, 0);
}

// 8 f32 -> hi/lo fp16 split: x ~= hi + lo to ~2^-22 rel.
__device__ __forceinline__ void split8(const f32x4 a, const f32x4 b,
                                       half8& hi, half8& lo) {
#pragma unroll
    for (int i = 0; i < 4; ++i) {
        hi[i]     = (_Float16)a[i];
        lo[i]     = (_Float16)(a[i] - (float)hi[i]);
        hi[4 + i] = (_Float16)b[i];
        lo[4 + i] = (_Float16)(b[i] - (float)hi[4 + i]);
    }
}

// Pre-split W (Wh,Wt: 256x256 f32) into granule-swizzled f16 hi/lo:
// dst[r*512 + c*64 + g'*8 ..+8), g = part*4+seg, g' = g ^ (r&7).
__global__ void presplit_w(const float* __restrict__ Wh, const float* __restrict__ Wt,
                           _Float16* __restrict__ Whs, _Float16* __restrict__ Wts)
{
    const int g = blockIdx.x * 256 + threadIdx.x;
    const int m = g >> 5;                  // 0..511
    const int cs = g & 31;
    const int c = cs >> 2, seg = cs & 3;
    const float* src = (m < 256) ? Wh : Wt;
    _Float16* dst    = (m < 256) ? Whs : Wts;
    const int r = m & 255;

    const float* s = src + (size_t)r * EMB + c * 32 + seg * 8;
    const f32x4 v0 = *(const f32x4*)s;
    const f32x4 v1 = *(const f32x4*)(s + 4);
    half8 hi, lo;
    split8(v0, v1, hi, lo);
    _Float16* d = dst + (size_t)r * 512 + c * 64;
    const int sw = r & 7;
    *(half8*)(d + ((seg       ^ sw) << 3)) = hi;
    *(half8*)(d + (((4 + seg) ^ sw) << 3)) = lo;
}

// Single-output GEMM with T3-minimal double-buffered pipeline.
// Each block -> one 128x128 tile of H = X*Wh^T + bh OR T = X*Wt^T + bt
// (variant = wg&3: bit0 = n-half, bit1 = head/tail). 3-term split-f16 MFMA.
// A staged as raw f32 via global_load_lds (granule swizzle baked into the
// per-lane GLOBAL source address); hi/lo split happens at frag-read time
// (VALU pipe, overlaps MFMA). B staged from pre-split f16 (zero in-loop VALU).
// Loop: STAGE(next chunk -> buf^1) issued BEFORE compute(buf), then ONE
// __syncthreads (vmcnt0+lgkm0+barrier) per chunk -> loads get the whole
// compute phase (~900cy) of latency cover (T3-minimal recipe, §5.5).
__global__ __launch_bounds__(256, 2)
void gemm_single(const float* __restrict__ X,
                 const _Float16* __restrict__ Whs, const _Float16* __restrict__ Wts,
                 const float* __restrict__ bh, const float* __restrict__ bt,
                 float* __restrict__ Hout, float* __restrict__ Tout,
                 int M, int nwg)
{
    __shared__ __align__(16) float    Af[2][128 * 32];   // 2 x 16 KB (f32 A)
    __shared__ __align__(16) _Float16 Bf[2][128 * 64];   // 2 x 16 KB (f16 hi/lo B)

    // bijective XCD swizzle (m204): keeps the 4 variants of an m-tile on one XCD
    const int fl = blockIdx.x;
    const int q = nwg >> 3, r = nwg & 7;
    const int xcd = fl & 7, ix = fl >> 3;
    const int wg = (xcd < r) ? xcd * (q + 1) + ix
                             : r * (q + 1) + (xcd - r) * q + ix;
    const int variant = wg & 3;
    const int m0 = (wg >> 2) << 7;
    const int n0 = (variant & 1) << 7;
    const int sel = variant >> 1;
    const _Float16* __restrict__ Ws = sel ? Wts : Whs;
    const float* __restrict__ bias  = sel ? bt : bh;
    float* __restrict__ OUT         = sel ? Tout : Hout;

    const int tid = threadIdx.x;
    const int lane = tid & 63;
    const int wv = tid >> 6;
    const int wm = (wv >> 1) << 6;     // 0 / 64
    const int wn = (wv & 1) << 6;      // 0 / 64
    const int l15 = lane & 15, l4 = lane >> 4;

    // staging map: thread -> row = (tid>>3)+32i, granule sg = tid&7
    const int srow = tid >> 3;
    const int sg = tid & 7;
    // per-issue constants
    int aSrcOff[4];   // byte offset within X row-chunk (swizzled granule)
    const char* bSrc0 = (const char*)Ws + (size_t)(n0 + srow) * 1024 + sg * 16;
#pragma unroll
    for (int i = 0; i < 4; ++i) {
        const int row = srow + (i << 5);
        aSrcOff[i] = (sg ^ (row & 7)) << 4;
    }
    const int ldOff = srow * 128 + sg * 16;   // linear LDS byte offset

    f32x4 acc[4][4];
#pragma unroll
    for (int i = 0; i < 4; ++i)
#pragma unroll
        for (int j = 0; j < 4; ++j) acc[i][j] = (f32x4){0.f, 0.f, 0.f, 0.f};

    // stage chunk c into buffer b
    auto STAGE = [&](int b, int c) {
        const int cb = c << 7;
#pragma unroll
        for (int i = 0; i < 4; ++i) {
            const int row = srow + (i << 5);
            const int gm = m0 + row;
            const int gmc = gm < M ? gm : M - 1;   // clamp; rows >= M never stored
            gload_lds16((const char*)X + (size_t)gmc * 1024 + cb + aSrcOff[i],
                        (char*)&Af[b][0] + ldOff + (i << 12));
            gload_lds16(bSrc0 + (size_t)i * 32768 + cb,
                        (char*)&Bf[b][0] + ldOff + (i << 12));
        }
    };

    STAGE(0, 0);
    __syncthreads();                   // chunk-0 tiles visible

    for (int c = 0; c < 8; ++c) {
        const int buf = c & 1;
        if (c < 7) STAGE(buf ^ 1, c + 1);   // issue next-chunk loads FIRST

        // ---- compute chunk c from buf ----
        const char* Ab = (const char*)&Af[buf][0];
        const char* Bb = (const char*)&Bf[buf][0];

        half8 ahh[4], ahl[4];
#pragma unroll
        for (int fi = 0; fi < 4; ++fi) {
            const int row = wm + fi * 16 + l15;
            const char* rb = Ab + row * 128;
            const f32x4 a0 = *(const f32x4*)(rb + (((l4 << 1)      ^ (row & 7)) << 4));
            const f32x4 a1 = *(const f32x4*)(rb + ((((l4 << 1) | 1) ^ (row & 7)) << 4));
            split8(a0, a1, ahh[fi], ahl[fi]);
        }
#pragma unroll
        for (int j = 0; j < 4; ++j) {
            const int n = wn + j * 16 + l15;
            const int n7 = n & 7;
            const char* nb = Bb + n * 128;
            const half8 bhh = *(const half8*)(nb + (((l4    ) ^ n7) << 4));
            const half8 bhl = *(const half8*)(nb + (((l4 + 4) ^ n7) << 4));
#pragma unroll
            for (int i = 0; i < 4; ++i) {
                acc[i][j] = __builtin_amdgcn_mfma_f32_16x16x32_f16(ahh[i], bhh, acc[i][j], 0, 0, 0);
                acc[i][j] = __builtin_amdgcn_mfma_f32_16x16x32_f16(ahh[i], bhl, acc[i][j], 0, 0, 0);
                acc[i][j] = __builtin_amdgcn_mfma_f32_16x16x32_f16(ahl[i], bhh, acc[i][j], 0, 0, 0);
            }
        }
        __syncthreads();   // vmcnt(0)+lgkm(0)+barrier: next tiles ready, reads done
    }

    // epilogue: C/D layout col = lane&15, row = (lane>>4)*4 + reg (m89)
    float bv[4];
#pragma unroll
    for (int j = 0; j < 4; ++j) bv[j] = bias[n0 + wn + j * 16 + l15];

#pragma unroll
    for (int i = 0; i < 4; ++i) {
        const int rbase = m0 + wm + i * 16 + l4 * 4;
#pragma unroll
        for (int rg = 0; rg < 4; ++rg) {
            const int gr = rbase + rg;
            if (gr < M) {
                float* dst = &OUT[(size_t)gr * EMB + n0 + wn];
#pragma unroll
                for (int j = 0; j < 4; ++j)
                    dst[j * 16 + l15] = acc[i][j][rg] + bv[j];
            }
        }
    }
}

// Two edges per wave: 6 outstanding row-gathers/wave for latency hiding.
__global__ __launch_bounds__(256)
void edge_score2(const float* __restrict__ H, const float* __restrict__ T,
                 const float* __restrict__ rel, const int* __restrict__ ei,
                 const int* __restrict__ et, float* __restrict__ out, int E)
{
    const int lane = threadIdx.x & 63;
    const int wid = threadIdx.x >> 6;
    const int e0 = (blockIdx.x * 4 + wid) * 2;
    if (e0 >= E) return;
    const bool two = (e0 + 1) < E;
    const int e1 = two ? e0 + 1 : e0;

    const int s0 = ei[e0], s1 = ei[e1];
    const int d0 = ei[E + e0], d1 = ei[E + e1];
    const int r0 = et[e0], r1 = et[e1];

    const int lo = lane * 4;
    const float4 h0 = *(const float4*)&H[(size_t)s0 * EMB + lo];
    const float4 h1 = *(const float4*)&H[(size_t)s1 * EMB + lo];
    const float4 t0 = *(const float4*)&T[(size_t)d0 * EMB + lo];
    const float4 t1 = *(const float4*)&T[(size_t)d1 * EMB + lo];
    const float4 g0 = *(const float4*)&rel[(size_t)r0 * EMB + lo];
    const float4 g1 = *(const float4*)&rel[(size_t)r1 * EMB + lo];

    float p0 = h0.x * g0.x * t0.x + h0.y * g0.y * t0.y
             + h0.z * g0.z * t0.z + h0.w * g0.w * t0.w;
    float p1 = h1.x * g1.x * t1.x + h1.y * g1.y * t1.y
             + h1.z * g1.z * t1.z + h1.w * g1.w * t1.w;
#pragma unroll
    for (int off = 32; off > 0; off >>= 1) {
        p0 += __shfl_xor(p0, off, 64);
        p1 += __shfl_xor(p1, off, 64);
    }
    if (lane == 0) {
        out[e0] = 1.0f / (1.0f + expf(-p0));
        if (two) out[e1] = 1.0f / (1.0f + expf(-p1));
    }
}

// Last-resort fallback: one block per edge, direct fp32 matvecs.
__global__ __launch_bounds__(256)
void edge_direct(const float* __restrict__ X, const int* __restrict__ ei,
                 const int* __restrict__ et,
                 const float* __restrict__ Wh, const float* __restrict__ bh,
                 const float* __restrict__ Wt, const float* __restrict__ bt,
                 const float* __restrict__ rel, float* __restrict__ out, int E)
{
    __shared__ float xsrc[EMB], xdst[EMB];
    __shared__ float red[256];
    const int e = blockIdx.x;
    const int tid = threadIdx.x;
    const int src = ei[e], dst = ei[E + e], r = et[e];

    xsrc[tid] = X[(size_t)src * EMB + tid];
    xdst[tid] = X[(size_t)dst * EMB + tid];
    __syncthreads();

    float ah = 0.f, at = 0.f;
    const float* wh = Wh + (size_t)tid * EMB;
    const float* wt = Wt + (size_t)tid * EMB;
#pragma unroll 8
    for (int k = 0; k < EMB; k += 4) {
        float4 w4 = *(const float4*)&wh[k];
        ah += w4.x * xsrc[k] + w4.y * xsrc[k + 1] + w4.z * xsrc[k + 2] + w4.w * xsrc[k + 3];
        float4 v4 = *(const float4*)&wt[k];
        at += v4.x * xdst[k] + v4.y * xdst[k + 1] + v4.z * xdst[k + 2] + v4.w * xdst[k + 3];
    }
    red[tid] = (ah + bh[tid]) * rel[(size_t)r * EMB + tid] * (at + bt[tid]);
    __syncthreads();
    for (int s2 = 128; s2 > 0; s2 >>= 1) {
        if (tid < s2) red[tid] += red[tid + s2];
        __syncthreads();
    }
    if (tid == 0) out[e] = 1.0f / (1.0f + expf(-red[0]));
}

extern "C" void kernel_launch(void* const* d_in, const int* in_sizes, int n_in,
                              void* d_out, int out_size, void* d_ws, size_t ws_size,
                              hipStream_t stream) {
    const float* x   = (const float*)d_in[0];
    const int*   ei  = (const int*)d_in[1];
    const int*   et  = (const int*)d_in[2];
    const float* Wh  = (const float*)d_in[3];
    const float* bh  = (const float*)d_in[4];
    const float* Wt  = (const float*)d_in[5];
    const float* bt  = (const float*)d_in[6];
    const float* rel = (const float*)d_in[7];
    float* out = (float*)d_out;

    const int M = in_sizes[0] / EMB;   // 100000 nodes
    const int E = in_sizes[2];         // 250000 edges

    const size_t szHT = (size_t)2 * M * EMB * sizeof(float);        // H + T
    const size_t szWs = (size_t)2 * 256 * 512 * sizeof(_Float16);   // Whs+Wts

    if (ws_size >= szHT + szWs) {
        float* H = (float*)d_ws;
        float* T = H + (size_t)M * EMB;
        _Float16* Whs = (_Float16*)((char*)d_ws + szHT);
        _Float16* Wts = Whs + (size_t)256 * 512;

        presplit_w<<<64, 256, 0, stream>>>(Wh, Wt, Whs, Wts);
        const int mtiles = (M + 127) / 128;
        const int nwg = 4 * mtiles;
        gemm_single<<<nwg, 256, 0, stream>>>(x, Whs, Wts, bh, bt, H, T, M, nwg);
        edge_score2<<<(E + 7) / 8, 256, 0, stream>>>(H, T, rel, ei, et, out, E);
    } else {
        edge_direct<<<E, 256, 0, stream>>>(x, ei, et, Wh, bh, Wt, bt, rel, out, E);
    }
}